// Round 3
// baseline (737.055 us; speedup 1.0000x reference)
//
#include <hip/hip_runtime.h>

#define N_NODES   100000
#define N_EDGES   3200000
#define N_FEAT    128
#define HIDDEN    16
#define N_CLASSES 10
#define N_GRAPHS  64

#define NBUCK     391          // ceil(N_NODES/256), bucket = dst >> 8
#define CAP       9216         // staging capacity per bucket (mean 8192, +11 sigma)
#define BINA_EPB  8192         // edges per block in k_binA (512 thr x 16)
#define BINA_BLOCKS ((N_EDGES + BINA_EPB - 1) / BINA_EPB)   // 391

// Workspace layout (4-byte units):
//   gcur  : [0,        512)       int, per-bucket staging cursor
//   dinv  : [512,      100512)    float
//   stage : [100512,   3703968)   int, 391*9216 packed (src<<8 | dst&255)
//   h1pA  : [3703968,  4503968)   float [N][8]  ch 0-7 of (x@W1)*dinv[row]
//   h1pB  : [4503968,  5303968)   float [N][8]  ch 8-15
//   h2pA  : [5303968,  6103968)   float [N][8]  ch 0-7 of layer-2 features
//   h2pB  : [6103968,  6303968)   float [N][2]  ch 8-9
//   out2  : overlays h1pA (dead after k_agg1): [N][10]
// total ~25.2 MB

__global__ __launch_bounds__(512) void k_ginit(int* __restrict__ gcur) {
    int t = threadIdx.x;
    if (t < NBUCK) gcur[t] = t * CAP;
}

// Bin edges by dst>>8 into per-bucket staging. Per block: LDS histogram of
// 8192 edges -> ONE global atomic per bucket reserves a contiguous run
// (~21 edges = 84B) -> LDS-cursor scatter. Edges cached in registers.
__global__ __launch_bounds__(512) void k_binA(const int* __restrict__ src,
                                              const int* __restrict__ dst,
                                              int* __restrict__ gcur,
                                              int* __restrict__ stage) {
    __shared__ int hist[NBUCK];
    __shared__ int curb[NBUCK];
    int tid = threadIdx.x;
    long long base = (long long)blockIdx.x * BINA_EPB;
    for (int t = tid; t < NBUCK; t += 512) hist[t] = 0;
    __syncthreads();
    int se[16], de[16];
#pragma unroll
    for (int i = 0; i < 16; ++i) {
        long long e = base + i * 512 + tid;
        if (e < N_EDGES) {
            se[i] = src[e];
            de[i] = dst[e];
            atomicAdd(&hist[de[i] >> 8], 1);
        } else {
            de[i] = -1;
        }
    }
    __syncthreads();
    for (int t = tid; t < NBUCK; t += 512) {
        int h = hist[t];
        curb[t] = h ? atomicAdd(&gcur[t], h) : 0;
    }
    __syncthreads();
#pragma unroll
    for (int i = 0; i < 16; ++i) {
        if (de[i] >= 0) {
            int b = de[i] >> 8;
            int p = atomicAdd(&curb[b], 1);
            stage[p] = (se[i] << 8) | (de[i] & 255);
        }
    }
}

// One block per bucket: LDS histogram of local dst -> dinv.
__global__ __launch_bounds__(256) void k_deg(const int* __restrict__ gcur,
                                             const int* __restrict__ stage,
                                             float* __restrict__ dinv) {
    __shared__ int hist[256];
    int b = blockIdx.x, t = threadIdx.x;
    int cnt = gcur[b] - b * CAP;
    const int* st = stage + b * CAP;
    hist[t] = 0;
    __syncthreads();
    for (int i = t; i < cnt; i += 256) atomicAdd(&hist[st[i] & 255], 1);
    __syncthreads();
    int n = b * 256 + t;
    if (n < N_NODES) dinv[n] = rsqrtf((float)hist[t] + 1.0f);
}

// 16 nodes per block: h1p[n][c] = (x[n] @ W1)[c] * dinv[n], split-stored.
__global__ __launch_bounds__(256) void k_gemm1(const float* __restrict__ x,
                                               const float* __restrict__ W1,
                                               const float* __restrict__ dinv,
                                               float* __restrict__ h1pA,
                                               float* __restrict__ h1pB) {
    __shared__ float w[N_FEAT * HIDDEN];   // 8 KB
    __shared__ float xs[16 * N_FEAT];      // 8 KB
    __shared__ float ds[16];
    int tid  = threadIdx.x;
    int base = blockIdx.x * 16;
    if (tid < 16) ds[tid] = dinv[base + tid];
    const float4* w4 = (const float4*)W1;
    float4*       wd = (float4*)w;
    wd[tid]       = w4[tid];
    wd[256 + tid] = w4[256 + tid];
    const float4* x4 = (const float4*)(x + (long long)base * N_FEAT);
    float4*       xd = (float4*)xs;
    xd[tid]       = x4[tid];
    xd[256 + tid] = x4[256 + tid];
    __syncthreads();
    int n = tid >> 4, c = tid & 15;
    const float* xr = &xs[n * N_FEAT];
    float acc = 0.f;
#pragma unroll
    for (int k = 0; k < N_FEAT; ++k) acc += xr[k] * w[k * HIDDEN + c];
    float v = acc * ds[n];
    int nn = base + n;
    if (c < 8) h1pA[nn * 8 + c] = v;
    else       h1pB[nn * 8 + (c - 8)] = v;
}

// One block per bucket: LDS-accumulate layer-1 aggregation (channel-split
// passes so each 3.2MB gather table is L2-resident), then fused
// bias + ReLU + @W2 + dinv scale -> split h2p tables.
__global__ __launch_bounds__(512) void k_agg1(const int* __restrict__ gcur,
                                              const int* __restrict__ stage,
                                              const float* __restrict__ dinv,
                                              const float* __restrict__ h1pA,
                                              const float* __restrict__ h1pB,
                                              const float* __restrict__ b1,
                                              const float* __restrict__ W2,
                                              float* __restrict__ h2pA,
                                              float* __restrict__ h2pB) {
    __shared__ float accA[256][9];
    __shared__ float accB[256][9];
    __shared__ float w2s[HIDDEN * N_CLASSES];
    int b = blockIdx.x, tid = threadIdx.x;
    int cnt = gcur[b] - b * CAP;
    const int* st = stage + b * CAP;
    int nbase = b * 256;
    // init acc with the self-loop rows (coalesced)
    for (int idx = tid; idx < 256 * 8; idx += 512) {
        int nl = idx >> 3, c = idx & 7;
        int n = nbase + nl;
        accA[nl][c] = (n < N_NODES) ? h1pA[n * 8 + c] : 0.f;
        accB[nl][c] = (n < N_NODES) ? h1pB[n * 8 + c] : 0.f;
    }
    if (tid < HIDDEN * N_CLASSES) w2s[tid] = W2[tid];
    __syncthreads();
    int c = tid & 7, e0 = tid >> 3;          // 64 edges in flight
    for (int i = e0; i < cnt; i += 64) {     // pass A: table h1pA (3.2MB, L2)
        int v = st[i];
        atomicAdd(&accA[v & 255][c], h1pA[(v >> 8) * 8 + c]);
    }
    for (int i = e0; i < cnt; i += 64) {     // pass B: table h1pB
        int v = st[i];
        atomicAdd(&accB[v & 255][c], h1pB[(v >> 8) * 8 + c]);
    }
    __syncthreads();
    if (tid < 256) {
        int n = nbase + tid;
        if (n < N_NODES) {
            float dn = dinv[n];
            float r[HIDDEN];
#pragma unroll
            for (int k = 0; k < 8; ++k) {
                r[k]     = fmaxf(dn * accA[tid][k] + b1[k], 0.f);
                r[k + 8] = fmaxf(dn * accB[tid][k] + b1[k + 8], 0.f);
            }
            float o[N_CLASSES];
#pragma unroll
            for (int j = 0; j < N_CLASSES; ++j) o[j] = 0.f;
#pragma unroll
            for (int k = 0; k < HIDDEN; ++k) {
                float rk = r[k];
#pragma unroll
                for (int j = 0; j < N_CLASSES; ++j) o[j] += rk * w2s[k * N_CLASSES + j];
            }
#pragma unroll
            for (int j = 0; j < 8; ++j) h2pA[n * 8 + j] = dn * o[j];
            h2pB[n * 2 + 0] = dn * o[8];
            h2pB[n * 2 + 1] = dn * o[9];
        }
    }
}

// One block per bucket: layer-2 aggregation (8-ch pass over h2pA = 3.2MB L2
// table, 2-ch pass over h2pB = 0.8MB table), writes final per-node [N][10].
__global__ __launch_bounds__(512) void k_agg2(const int* __restrict__ gcur,
                                              const int* __restrict__ stage,
                                              const float* __restrict__ dinv,
                                              const float* __restrict__ h2pA,
                                              const float* __restrict__ h2pB,
                                              float* __restrict__ out2) {
    __shared__ float accA[256][9];
    __shared__ float accB[256][3];
    int b = blockIdx.x, tid = threadIdx.x;
    int cnt = gcur[b] - b * CAP;
    const int* st = stage + b * CAP;
    int nbase = b * 256;
    for (int idx = tid; idx < 256 * 8; idx += 512) {
        int nl = idx >> 3, c = idx & 7;
        int n = nbase + nl;
        accA[nl][c] = (n < N_NODES) ? h2pA[n * 8 + c] : 0.f;
    }
    for (int idx = tid; idx < 256 * 2; idx += 512) {
        int nl = idx >> 1, c = idx & 1;
        int n = nbase + nl;
        accB[nl][c] = (n < N_NODES) ? h2pB[n * 2 + c] : 0.f;
    }
    __syncthreads();
    int c = tid & 7, e0 = tid >> 3;
    for (int i = e0; i < cnt; i += 64) {     // pass A: 8 channels
        int v = st[i];
        atomicAdd(&accA[v & 255][c], h2pA[(v >> 8) * 8 + c]);
    }
    int c2 = tid & 1, e2 = tid >> 1;
    for (int i = e2; i < cnt; i += 256) {    // pass B: 2 channels
        int v = st[i];
        atomicAdd(&accB[v & 255][c2], h2pB[(v >> 8) * 2 + c2]);
    }
    __syncthreads();
    if (tid < 256) {
        int n = nbase + tid;
        if (n < N_NODES) {
            float dn = dinv[n];
#pragma unroll
            for (int j = 0; j < 8; ++j) out2[n * 10 + j] = dn * accA[tid][j];
            out2[n * 10 + 8] = dn * accB[tid][0];
            out2[n * 10 + 9] = dn * accB[tid][1];
        }
    }
}

// one block per graph; batch sorted -> binary search the node range,
// block-reduce sums, mean + b2, log_softmax straight to d_out.
__global__ __launch_bounds__(256) void k_pool(const float* __restrict__ out2,
                                              const float* __restrict__ b2,
                                              const int* __restrict__ batch,
                                              float* __restrict__ out) {
    __shared__ float red[N_CLASSES][256];
    int g = blockIdx.x, tid = threadIdx.x;
    int lo = 0, hi = N_NODES;
    while (lo < hi) { int m = (lo + hi) >> 1; if (batch[m] < g) lo = m + 1; else hi = m; }
    int start = lo;
    lo = 0; hi = N_NODES;
    while (lo < hi) { int m = (lo + hi) >> 1; if (batch[m] < g + 1) lo = m + 1; else hi = m; }
    int end = lo;

    float sum[N_CLASSES];
#pragma unroll
    for (int j = 0; j < N_CLASSES; ++j) sum[j] = 0.f;
    for (int i = start + tid; i < end; i += 256) {
        const float* r = &out2[(long long)i * 10];
#pragma unroll
        for (int j = 0; j < N_CLASSES; ++j) sum[j] += r[j];
    }
#pragma unroll
    for (int j = 0; j < N_CLASSES; ++j) red[j][tid] = sum[j];
    __syncthreads();
    for (int s = 128; s > 0; s >>= 1) {
        if (tid < s) {
#pragma unroll
            for (int j = 0; j < N_CLASSES; ++j) red[j][tid] += red[j][tid + s];
        }
        __syncthreads();
    }
    if (tid == 0) {
        int cnt = end - start;
        float v[N_CLASSES];
        if (cnt > 0) {
            float inv = 1.f / (float)cnt;
#pragma unroll
            for (int j = 0; j < N_CLASSES; ++j) v[j] = red[j][0] * inv + b2[j];
        } else {
#pragma unroll
            for (int j = 0; j < N_CLASSES; ++j) v[j] = 0.f;
        }
        float m = v[0];
#pragma unroll
        for (int j = 1; j < N_CLASSES; ++j) m = fmaxf(m, v[j]);
        float l = 0.f;
#pragma unroll
        for (int j = 0; j < N_CLASSES; ++j) l += expf(v[j] - m);
        l = logf(l);
#pragma unroll
        for (int j = 0; j < N_CLASSES; ++j) out[g * N_CLASSES + j] = v[j] - m - l;
    }
}

extern "C" void kernel_launch(void* const* d_in, const int* in_sizes, int n_in,
                              void* d_out, int out_size, void* d_ws, size_t ws_size,
                              hipStream_t stream) {
    const float* x     = (const float*)d_in[0];
    const int*   edge  = (const int*)d_in[1];   // [2, E]
    const int*   batch = (const int*)d_in[2];
    const float* W1    = (const float*)d_in[3];
    const float* b1    = (const float*)d_in[4];
    const float* W2    = (const float*)d_in[5];
    const float* b2    = (const float*)d_in[6];
    float* out = (float*)d_out;
    float* ws  = (float*)d_ws;

    int*   gcur  = (int*)ws;                  // [0, 512)
    float* dinv  = ws + 512;                  // [512, 100512)
    int*   stage = (int*)(ws + 100512);       // 391*9216
    float* h1pA  = ws + 3703968;              // [N][8]
    float* h1pB  = ws + 4503968;              // [N][8]
    float* h2pA  = ws + 5303968;              // [N][8]
    float* h2pB  = ws + 6103968;              // [N][2]
    float* out2  = h1pA;                      // h1p dead after k_agg1

    const int* srcp = edge;
    const int* dstp = edge + N_EDGES;

    k_ginit<<<1, 512, 0, stream>>>(gcur);
    k_binA<<<BINA_BLOCKS, 512, 0, stream>>>(srcp, dstp, gcur, stage);
    k_deg<<<NBUCK, 256, 0, stream>>>(gcur, stage, dinv);
    k_gemm1<<<N_NODES / 16, 256, 0, stream>>>(x, W1, dinv, h1pA, h1pB);
    k_agg1<<<NBUCK, 512, 0, stream>>>(gcur, stage, dinv, h1pA, h1pB, b1, W2, h2pA, h2pB);
    k_agg2<<<NBUCK, 512, 0, stream>>>(gcur, stage, dinv, h2pA, h2pB, out2);
    k_pool<<<N_GRAPHS, 256, 0, stream>>>(out2, b2, batch, out);
}

// Round 4
// 282.063 us; speedup vs baseline: 2.6131x; 2.6131x over previous
//
#include <hip/hip_runtime.h>

#define N_NODES   100000
#define N_EDGES   3200000
#define N_FEAT    128
#define HIDDEN    16
#define N_CLASSES 10
#define N_GRAPHS  64

#define NBUCK     391          // ceil(N_NODES/256), bucket = dst >> 8
#define CAP       9216         // staging capacity per bucket (mean 8192, +11 sigma)
#define BINA_EPB  8192         // edges per block in k_binA (512 thr x 16)
#define BINA_BLOCKS ((N_EDGES + BINA_EPB - 1) / BINA_EPB)   // 391

// Workspace layout (4-byte units):
//   gcur   : [0,        512)       int, per-bucket staging cursor
//   bbase  : [512,      1024)      int, per-bucket CSR base
//   pooled : [1024,     2048)      float [64][16], zeroed each launch
//   dinv   : [2048,     102048)    float
//   off    : [102048,   202080)    int (100001 used)
//   srcs   : [202080,   3402080)   int, CSR by dst
//   stage  : [3402080,  7005536)   int, 391*9216 packed (src<<8 | dst&255)
//   h1p    : [3402080,  5002080)   float [N][16] (overlays stage; stage dead)
//   h2p    : [5002080,  6602080)   float [N][16] (c>=10 zero)
// total ~28.0 MB

__global__ __launch_bounds__(512) void k_ginit(int* __restrict__ gcur,
                                               float* __restrict__ pooled) {
    int t = threadIdx.x;
    if (t < NBUCK) gcur[t] = t * CAP;
    pooled[t] = 0.f;
    pooled[t + 512] = 0.f;
}

// Bin edges by dst>>8 into per-bucket staging. Per block: LDS histogram of
// 8192 edges -> ONE global atomic per bucket reserves a contiguous run
// (~21 edges = 84B) -> LDS-cursor scatter. Edges cached in registers.
__global__ __launch_bounds__(512) void k_binA(const int* __restrict__ src,
                                              const int* __restrict__ dst,
                                              int* __restrict__ gcur,
                                              int* __restrict__ stage) {
    __shared__ int hist[NBUCK];
    __shared__ int curb[NBUCK];
    int tid = threadIdx.x;
    long long base = (long long)blockIdx.x * BINA_EPB;
    for (int t = tid; t < NBUCK; t += 512) hist[t] = 0;
    __syncthreads();
    int se[16], de[16];
#pragma unroll
    for (int i = 0; i < 16; ++i) {
        long long e = base + i * 512 + tid;
        if (e < N_EDGES) {
            se[i] = src[e];
            de[i] = dst[e];
            atomicAdd(&hist[de[i] >> 8], 1);
        } else {
            de[i] = -1;
        }
    }
    __syncthreads();
    for (int t = tid; t < NBUCK; t += 512) {
        int h = hist[t];
        curb[t] = h ? atomicAdd(&gcur[t], h) : 0;
    }
    __syncthreads();
#pragma unroll
    for (int i = 0; i < 16; ++i) {
        if (de[i] >= 0) {
            int b = de[i] >> 8;
            int p = atomicAdd(&curb[b], 1);
            stage[p] = (se[i] << 8) | (de[i] & 255);
        }
    }
}

// Exclusive scan of bucket counts -> per-bucket CSR base.
__global__ __launch_bounds__(512) void k_bscan(const int* __restrict__ gcur,
                                               int* __restrict__ bbase,
                                               int* __restrict__ off) {
    __shared__ int s[512];
    int t = threadIdx.x;
    int c = (t < NBUCK) ? (gcur[t] - t * CAP) : 0;
    s[t] = c;
    __syncthreads();
    for (int o = 1; o < 512; o <<= 1) {
        int a = (t >= o) ? s[t - o] : 0;
        __syncthreads();
        s[t] += a;
        __syncthreads();
    }
    if (t < NBUCK) bbase[t] = s[t] - c;
    if (t == 0) off[N_NODES] = N_EDGES;
}

// One block per bucket: per-node histogram + scan -> off/dinv, then place
// each staged edge at its final CSR slot (all writes within the bucket's
// ~36 KB CSR window -> L2-resident, lines fill).
__global__ __launch_bounds__(256) void k_binB(const int* __restrict__ gcur,
                                              const int* __restrict__ bbase,
                                              const int* __restrict__ stage,
                                              int* __restrict__ off,
                                              float* __restrict__ dinv,
                                              int* __restrict__ srcs) {
    __shared__ int hist[256];
    __shared__ int excl[256];
    int b = blockIdx.x, t = threadIdx.x;
    int cnt   = gcur[b] - b * CAP;
    int sbase = b * CAP;
    int cbase = bbase[b];
    hist[t] = 0;
    __syncthreads();
    for (int i = t; i < cnt; i += 256) {
        int v = stage[sbase + i];
        atomicAdd(&hist[v & 255], 1);
    }
    __syncthreads();
    int c = hist[t];
    excl[t] = c;
    __syncthreads();
    for (int o = 1; o < 256; o <<= 1) {
        int a = (t >= o) ? excl[t - o] : 0;
        __syncthreads();
        excl[t] += a;
        __syncthreads();
    }
    int ex = excl[t] - c;
    int node = b * 256 + t;
    if (node < N_NODES) {
        off[node]  = cbase + ex;
        dinv[node] = rsqrtf((float)c + 1.0f);
    }
    __syncthreads();
    hist[t] = ex;          // reuse as per-node cursor
    __syncthreads();
    for (int i = t; i < cnt; i += 256) {
        int v = stage[sbase + i];
        int p = cbase + atomicAdd(&hist[v & 255], 1);
        srcs[p] = v >> 8;
    }
}

// 16 nodes per block: h1p[n][c] = (x[n] @ W1)[c] * dinv[n]
__global__ __launch_bounds__(256) void k_gemm1(const float* __restrict__ x,
                                               const float* __restrict__ W1,
                                               const float* __restrict__ dinv,
                                               float* __restrict__ h1p) {
    __shared__ float w[N_FEAT * HIDDEN];   // 8 KB
    __shared__ float xs[16 * N_FEAT];      // 8 KB
    __shared__ float ds[16];
    int tid  = threadIdx.x;
    int base = blockIdx.x * 16;
    if (tid < 16) ds[tid] = dinv[base + tid];
    const float4* w4 = (const float4*)W1;
    float4*       wd = (float4*)w;
    wd[tid]       = w4[tid];
    wd[256 + tid] = w4[256 + tid];
    const float4* x4 = (const float4*)(x + (long long)base * N_FEAT);
    float4*       xd = (float4*)xs;
    xd[tid]       = x4[tid];
    xd[256 + tid] = x4[256 + tid];
    __syncthreads();
    int n = tid >> 4, c = tid & 15;
    const float* xr = &xs[n * N_FEAT];
    float acc = 0.f;
#pragma unroll
    for (int k = 0; k < N_FEAT; ++k) acc += xr[k] * w[k * HIDDEN + c];
    h1p[(base + n) * HIDDEN + c] = acc * ds[n];
}

// Fused: CSR gather of layer-1 aggregation + bias + ReLU + (@W2) + dinv scale.
// 16 lanes (channels) per node, 16 nodes per block.
__global__ __launch_bounds__(256) void k_agg1(const int* __restrict__ off,
                                              const int* __restrict__ srcs,
                                              const float* __restrict__ dinv,
                                              const float* __restrict__ h1p,
                                              const float* __restrict__ b1,
                                              const float* __restrict__ W2,
                                              float* __restrict__ h2p) {
    __shared__ float r_s[16][17];
    __shared__ float w2s[HIDDEN * N_CLASSES];
    int tid = threadIdx.x;
    if (tid < HIDDEN * N_CLASSES) w2s[tid] = W2[tid];
    int nl = tid >> 4, c = tid & 15;
    int n  = blockIdx.x * 16 + nl;
    int beg = off[n], end = off[n + 1];
    float a0 = h1p[n * 16 + c];            // self-loop
    float a1 = 0.f, a2 = 0.f, a3 = 0.f;
    int j = beg;
    for (; j + 3 < end; j += 4) {
        int s0 = srcs[j], s1 = srcs[j + 1], s2 = srcs[j + 2], s3 = srcs[j + 3];
        a0 += h1p[s0 * 16 + c];
        a1 += h1p[s1 * 16 + c];
        a2 += h1p[s2 * 16 + c];
        a3 += h1p[s3 * 16 + c];
    }
    for (; j < end; ++j) a0 += h1p[srcs[j] * 16 + c];
    float acc = (a0 + a1) + (a2 + a3);
    float dn  = dinv[n];
    r_s[nl][c] = fmaxf(dn * acc + b1[c], 0.f);
    __syncthreads();
    if (c < N_CLASSES) {
        float o = 0.f;
#pragma unroll
        for (int k = 0; k < HIDDEN; ++k) o += r_s[nl][k] * w2s[k * N_CLASSES + c];
        h2p[n * 16 + c] = dn * o;
    } else {
        h2p[n * 16 + c] = 0.f;
    }
}

// CSR gather of layer-2 aggregation, fused with graph pooling:
// per-node o[c] = dinv[n]*(sum_in h2p[s] + h2p[n]); block-reduce over the
// 16 consecutive nodes (batch sorted -> almost always one graph per block)
// and emit one coalesced 16-float atomicAdd into pooled[64][16].
__global__ __launch_bounds__(256) void k_agg2p(const int* __restrict__ off,
                                               const int* __restrict__ srcs,
                                               const float* __restrict__ dinv,
                                               const float* __restrict__ h2p,
                                               const int* __restrict__ batch,
                                               float* __restrict__ pooled) {
    __shared__ float red[16][17];
    int tid = threadIdx.x;
    int nl = tid >> 4, c = tid & 15;
    int nbase = blockIdx.x * 16;
    int n  = nbase + nl;
    int beg = off[n], end = off[n + 1];
    float a0 = h2p[n * 16 + c];            // self-loop
    float a1 = 0.f, a2 = 0.f, a3 = 0.f;
    int j = beg;
    for (; j + 3 < end; j += 4) {
        int s0 = srcs[j], s1 = srcs[j + 1], s2 = srcs[j + 2], s3 = srcs[j + 3];
        a0 += h2p[s0 * 16 + c];
        a1 += h2p[s1 * 16 + c];
        a2 += h2p[s2 * 16 + c];
        a3 += h2p[s3 * 16 + c];
    }
    for (; j < end; ++j) a0 += h2p[srcs[j] * 16 + c];
    float o = dinv[n] * ((a0 + a1) + (a2 + a3));   // c>=10: h2p is 0 -> o=0

    int g0  = batch[nbase];
    int g15 = batch[nbase + 15];
    if (g0 == g15) {                 // uniform branch: whole block one graph
        red[nl][c] = o;
        __syncthreads();
#pragma unroll
        for (int s = 8; s > 0; s >>= 1) {
            if (nl < s) red[nl][c] += red[nl + s][c];
            __syncthreads();
        }
        if (tid < N_CLASSES) atomicAdd(&pooled[g0 * 16 + tid], red[0][tid]);
    } else {                         // graph boundary inside block (rare)
        if (c < N_CLASSES) atomicAdd(&pooled[batch[n] * 16 + c], o);
    }
}

// one block, one thread per graph: counts via binary search on sorted batch,
// mean + b2, log_softmax -> out.
__global__ __launch_bounds__(64) void k_final(const float* __restrict__ pooled,
                                              const float* __restrict__ b2,
                                              const int* __restrict__ batch,
                                              float* __restrict__ out) {
    int g = threadIdx.x;
    if (g >= N_GRAPHS) return;
    int lo = 0, hi = N_NODES;
    while (lo < hi) { int m = (lo + hi) >> 1; if (batch[m] < g) lo = m + 1; else hi = m; }
    int start = lo;
    lo = 0; hi = N_NODES;
    while (lo < hi) { int m = (lo + hi) >> 1; if (batch[m] < g + 1) lo = m + 1; else hi = m; }
    int cnt = lo - start;

    float v[N_CLASSES];
    if (cnt > 0) {
        float inv = 1.f / (float)cnt;
#pragma unroll
        for (int j = 0; j < N_CLASSES; ++j) v[j] = pooled[g * 16 + j] * inv + b2[j];
    } else {
#pragma unroll
        for (int j = 0; j < N_CLASSES; ++j) v[j] = 0.f;
    }
    float m = v[0];
#pragma unroll
    for (int j = 1; j < N_CLASSES; ++j) m = fmaxf(m, v[j]);
    float l = 0.f;
#pragma unroll
    for (int j = 0; j < N_CLASSES; ++j) l += expf(v[j] - m);
    l = logf(l);
#pragma unroll
    for (int j = 0; j < N_CLASSES; ++j) out[g * N_CLASSES + j] = v[j] - m - l;
}

extern "C" void kernel_launch(void* const* d_in, const int* in_sizes, int n_in,
                              void* d_out, int out_size, void* d_ws, size_t ws_size,
                              hipStream_t stream) {
    const float* x     = (const float*)d_in[0];
    const int*   edge  = (const int*)d_in[1];   // [2, E]
    const int*   batch = (const int*)d_in[2];
    const float* W1    = (const float*)d_in[3];
    const float* b1    = (const float*)d_in[4];
    const float* W2    = (const float*)d_in[5];
    const float* b2    = (const float*)d_in[6];
    float* out = (float*)d_out;
    float* ws  = (float*)d_ws;

    int*   gcur   = (int*)ws;                  // [0, 512)
    int*   bbase  = (int*)(ws + 512);          // [512, 1024)
    float* pooled = ws + 1024;                 // [1024, 2048)
    float* dinv   = ws + 2048;                 // [2048, 102048)
    int*   off    = (int*)(ws + 102048);       // 100001 used
    int*   srcs   = (int*)(ws + 202080);       // 3.2M
    int*   stage  = (int*)(ws + 3402080);      // 391*9216
    float* h1p    = ws + 3402080;              // overlays stage (dead after binB)
    float* h2p    = ws + 5002080;

    const int* srcp = edge;
    const int* dstp = edge + N_EDGES;

    k_ginit<<<1, 512, 0, stream>>>(gcur, pooled);
    k_binA<<<BINA_BLOCKS, 512, 0, stream>>>(srcp, dstp, gcur, stage);
    k_bscan<<<1, 512, 0, stream>>>(gcur, bbase, off);
    k_binB<<<NBUCK, 256, 0, stream>>>(gcur, bbase, stage, off, dinv, srcs);
    k_gemm1<<<N_NODES / 16, 256, 0, stream>>>(x, W1, dinv, h1p);
    k_agg1<<<N_NODES / 16, 256, 0, stream>>>(off, srcs, dinv, h1p, b1, W2, h2p);
    k_agg2p<<<N_NODES / 16, 256, 0, stream>>>(off, srcs, dinv, h2p, batch, pooled);
    k_final<<<1, 64, 0, stream>>>(pooled, b2, batch, out);
}